// Round 3
// baseline (446.833 us; speedup 1.0000x reference)
//
#include <hip/hip_runtime.h>
#include <cstdint>
#include <cstddef>

// Problem dims (fixed by setup_inputs)
#define B_  8
#define S_  4096
#define D_  1024
#define H_  1024
#define M_  (B_*S_)          // 32768 GEMM rows
#define NT_ 2048             // interleaved N (k,p pairs at 16-col granularity)
#define NC_ 64               // scan chunks
#define L_  (S_/NC_)         // 64 steps per chunk

typedef __bf16 bf16x8 __attribute__((ext_vector_type(8)));
typedef float  f32x4  __attribute__((ext_vector_type(4)));
typedef uint16_t u16x8 __attribute__((ext_vector_type(8)));

__device__ __forceinline__ uint16_t f2bf(float f) {
  union { float f; uint32_t u; } v; v.f = f;
  uint32_t u = v.u;
  u += 0x7FFFu + ((u >> 16) & 1u);   // RNE
  return (uint16_t)(u >> 16);
}
__device__ __forceinline__ float gfun(float x) {
  // g(x) = x+0.5 if x>=0 else sigmoid(x)
  return x >= 0.0f ? x + 0.5f
                   : __builtin_amdgcn_rcpf(1.0f + __expf(-x));
}
__device__ __forceinline__ void unpack_cv(uint32_t u, float& c, float& v) {
  union { uint32_t u; _Float16 h[2]; } p; p.u = u;
  c = (float)p.h[0]; v = (float)p.h[1];
}

// ---------------- fused fp32 -> bf16 convert for x, and Wz/Wh -> interleaved Wc --
// Wc row layout: group g (0..63): rows 32g..32g+15 = Wz rows 16g..16g+15,
//                                 rows 32g+16..32g+31 = Wh rows 16g..16g+15.
#define X8_  (M_ * D_ / 8)
#define W8_  (H_ * D_ / 8)
#define TOT8_ (X8_ + 2 * W8_)
__global__ __launch_bounds__(256) void cvt_all_kernel(
    const float* __restrict__ x, const float* __restrict__ Wz,
    const float* __restrict__ Wh, uint16_t* __restrict__ xb,
    uint16_t* __restrict__ Wc) {
  int stride = gridDim.x * 256;
  for (int u = blockIdx.x * 256 + threadIdx.x; u < TOT8_; u += stride) {
    const float* src; uint16_t* dst;
    if (u < X8_) {
      src = x + (size_t)u * 8; dst = xb + (size_t)u * 8;
    } else if (u < X8_ + W8_) {
      int v = u - X8_;
      int r = v >> 7, c = v & 127;
      int row = ((r >> 4) << 5) | (r & 15);
      src = Wz + (size_t)v * 8;
      dst = Wc + (size_t)row * D_ + c * 8;
    } else {
      int v = u - X8_ - W8_;
      int r = v >> 7, c = v & 127;
      int row = ((r >> 4) << 5) | 16 | (r & 15);
      src = Wh + (size_t)v * 8;
      dst = Wc + (size_t)row * D_ + c * 8;
    }
    float4 a = ((const float4*)src)[0], b = ((const float4*)src)[1];
    u16x8 o;
    o[0] = f2bf(a.x); o[1] = f2bf(a.y); o[2] = f2bf(a.z); o[3] = f2bf(a.w);
    o[4] = f2bf(b.x); o[5] = f2bf(b.y); o[6] = f2bf(b.z); o[7] = f2bf(b.w);
    *(u16x8*)dst = o;
  }
}

// ---------------- 256x256-tile 8-wave phase-split GEMM + activation epilogue ----
// C = A(32768x1024) * Wc^T(2048x1024). 8 waves as 2(M)x4(N); per-wave 128x64.
// 4 phases per K-tile (BK=64): phase p computes m-pair {2p,2p+1} (16 MFMA).
// ONE barrier per phase (after the optional counted vmcnt). No hand lgkmcnt
// before MFMA: plain C++ ds-reads let the compiler emit fine-grained counted
// lgkmcnt interleaving reads with MFMAs; the single barrier lets waves drift
// so one wave's LDS reads overlap another's MFMA cluster (role-split).
// vmcnt ledger (per wave): enter p0 with 2 outstanding (A1,A3 of t);
// p0 +A0,A2(t+1)=4 | p1 +B0,B1=6, vmcnt(4)->t's A1,A3 landed | p2 +B2,B3=6 |
// p3 +A1,A3=8, vmcnt(2)->t+1's first-6 landed. Barrier AFTER vmcnt makes the
// per-wave confirmation global. Last K-tile peeled with a vmcnt(0) drain
// (counted-N arithmetic is wrong on a no-stage iteration — round-1 failure).
// Epilogue: tn even = k-frag, tn odd = p-frag for the SAME h columns (lane-local).
#define BK 64
__global__ __launch_bounds__(512, 2)
void fused_gemm_kernel(const uint16_t* __restrict__ A,
                       const uint16_t* __restrict__ Wc,
                       const float* __restrict__ bz,
                       const float* __restrict__ bh,
                       uint32_t* __restrict__ cv) {
  __shared__ __attribute__((aligned(16))) uint16_t sA[2][256 * BK];  // 2 x 32 KB
  __shared__ __attribute__((aligned(16))) uint16_t sB[2][256 * BK];  // 2 x 32 KB

  const int tid  = threadIdx.x;
  const int lane = tid & 63;
  const int wave = tid >> 6;
  const int wm = wave >> 2;        // 0..1  (M half)
  const int wn = wave & 3;         // 0..3  (N quarter)
  const int q  = lane >> 4;
  const int mn = lane & 15;

  // Bijective XCD swizzle: nwg=1024 (%8==0). Each XCD owns 16 contiguous
  // A row-panels (bx fastest within an XCD -> A panel stays L2-hot).
  const int bid  = blockIdx.x;
  const int tile = (bid & 7) * 128 + (bid >> 3);
  const int mTile = (tile >> 3) * 256;
  const int nTile = (tile & 7) * 256;

  // Staging addresses: load-unit L = 64 rows x 64 cols (8 KB = 512 thr x 16 B).
  // LDS dest is linear (tid*16 B); source col-unit pre-swizzled by cu^(r&7).
  const int rl = tid >> 3;         // 0..63 row within unit
  const int cu = tid & 7;          // 16B col-unit
  const int sw = cu ^ (rl & 7);
  const uint16_t* aSrc[4];
  const uint16_t* bSrc[4];
  #pragma unroll
  for (int L = 0; L < 4; L++) {
    aSrc[L] = A  + (size_t)(mTile + L * 64 + rl) * D_ + sw * 8;
    bSrc[L] = Wc + (size_t)(nTile + L * 64 + rl) * D_ + sw * 8;
  }
  const int ldsSlot = tid * 8;     // element offset inside the 4096-elem unit

  // Read-side bases (elements; row stride 64). r&7 == mn&7 for all fragments.
  const int swr = mn & 7;
  const int aBase = (wm * 128 + mn) * 64;
  const int bBase = (wn * 64  + mn) * 64;
  int koff[2];
  #pragma unroll
  for (int kk = 0; kk < 2; kk++) koff[kk] = ((kk * 4 + q) ^ swr) * 8;

#define STAGE_A(buf, kt, L)                                                    \
  __builtin_amdgcn_global_load_lds(                                            \
      (const __attribute__((address_space(1))) void*)(aSrc[L] + (kt) * BK),    \
      (__attribute__((address_space(3))) void*)&sA[buf][(L) * 4096 + ldsSlot], \
      16, 0, 0)
#define STAGE_B(buf, kt, L)                                                    \
  __builtin_amdgcn_global_load_lds(                                            \
      (const __attribute__((address_space(1))) void*)(bSrc[L] + (kt) * BK),    \
      (__attribute__((address_space(3))) void*)&sB[buf][(L) * 4096 + ldsSlot], \
      16, 0, 0)

  f32x4 acc[8][4] = {};

  // Prologue: tile 0 and tile 1, stream order A0,A2,B0,B1,B2,B3,A1,A3 each.
  STAGE_A(0, 0, 0); STAGE_A(0, 0, 2);
  STAGE_B(0, 0, 0); STAGE_B(0, 0, 1); STAGE_B(0, 0, 2); STAGE_B(0, 0, 3);
  STAGE_A(0, 0, 1); STAGE_A(0, 0, 3);
  STAGE_A(1, 1, 0); STAGE_A(1, 1, 2);
  STAGE_B(1, 1, 0); STAGE_B(1, 1, 1); STAGE_B(1, 1, 2); STAGE_B(1, 1, 3);
  STAGE_A(1, 1, 1); STAGE_A(1, 1, 3);
  asm volatile("s_waitcnt vmcnt(8)" ::: "memory");   // tile 0 fully landed
  __builtin_amdgcn_s_barrier();
  __builtin_amdgcn_sched_barrier(0);

  // Main loop over tiles 0..14 (tile 15 peeled).
  #pragma unroll 2
  for (int t = 0; t < D_ / BK - 1; ++t) {
    const int curb = t & 1, nxtb = curb ^ 1;
    const uint16_t* sAc = sA[curb];
    const uint16_t* sBc = sB[curb];
    const bool doStage = (t >= 1);
    const int kn = t + 1;

    bf16x8 bv[4][2];

    #pragma unroll
    for (int p = 0; p < 4; ++p) {
      // ds-reads for this phase (compiler inserts counted lgkmcnt before the
      // consuming MFMAs -> reads drain under the MFMA cluster).
      if (p == 0) {
        #pragma unroll
        for (int tn = 0; tn < 4; tn++)
          #pragma unroll
          for (int kk = 0; kk < 2; kk++)
            bv[tn][kk] = *(const bf16x8*)&sBc[bBase + tn * 1024 + koff[kk]];
      }
      bf16x8 av[2][2];
      #pragma unroll
      for (int mi = 0; mi < 2; mi++)
        #pragma unroll
        for (int kk = 0; kk < 2; kk++)
          av[mi][kk] =
              *(const bf16x8*)&sAc[aBase + (2 * p + mi) * 1024 + koff[kk]];

      // Stage tile t+1 into the other buffer, consumption-lead order.
      if (doStage) {
        if (p == 0) { STAGE_A(nxtb, kn, 0); STAGE_A(nxtb, kn, 2); }
        if (p == 1) { STAGE_B(nxtb, kn, 0); STAGE_B(nxtb, kn, 1); }
        if (p == 2) { STAGE_B(nxtb, kn, 2); STAGE_B(nxtb, kn, 3); }
        if (p == 3) { STAGE_A(nxtb, kn, 1); STAGE_A(nxtb, kn, 3); }
      }

      __builtin_amdgcn_s_setprio(1);
      #pragma unroll
      for (int mi = 0; mi < 2; mi++)
        #pragma unroll
        for (int tn = 0; tn < 4; tn++)
          #pragma unroll
          for (int kk = 0; kk < 2; kk++)
            acc[2 * p + mi][tn] = __builtin_amdgcn_mfma_f32_16x16x32_bf16(
                av[mi][kk], bv[tn][kk], acc[2 * p + mi][tn], 0, 0, 0);
      __builtin_amdgcn_s_setprio(0);

      // Counted waits (never 0), BEFORE the phase barrier so the per-wave
      // landing confirmation becomes workgroup-global:
      // p1 gates tile t's A1/A3 (read at p2); p3 gates t+1's first 6 units.
      if (p == 1) asm volatile("s_waitcnt vmcnt(4)" ::: "memory");
      if (p == 3) asm volatile("s_waitcnt vmcnt(2)" ::: "memory");
      __builtin_amdgcn_s_barrier();
      __builtin_amdgcn_sched_barrier(0);
    }
  }
#undef STAGE_A
#undef STAGE_B

  // ---- Peeled tail: tile 15 (buffer 1). Drain the last 2 in-flight loads
  // (A1,A3 of tile 15), barrier so ALL waves' contributions have landed, then
  // plain reads + MFMA — no staging, no LDS writes, so no further sync needed.
  asm volatile("s_waitcnt vmcnt(0)" ::: "memory");
  __builtin_amdgcn_s_barrier();
  __builtin_amdgcn_sched_barrier(0);
  {
    const uint16_t* sAc = sA[1];
    const uint16_t* sBc = sB[1];
    bf16x8 bv[4][2];
    #pragma unroll
    for (int tn = 0; tn < 4; tn++)
      #pragma unroll
      for (int kk = 0; kk < 2; kk++)
        bv[tn][kk] = *(const bf16x8*)&sBc[bBase + tn * 1024 + koff[kk]];
    __builtin_amdgcn_s_setprio(1);
    #pragma unroll
    for (int m = 0; m < 8; m++) {
      bf16x8 av[2];
      #pragma unroll
      for (int kk = 0; kk < 2; kk++)
        av[kk] = *(const bf16x8*)&sAc[aBase + m * 1024 + koff[kk]];
      #pragma unroll
      for (int tn = 0; tn < 4; tn++)
        #pragma unroll
        for (int kk = 0; kk < 2; kk++)
          acc[m][tn] = __builtin_amdgcn_mfma_f32_16x16x32_bf16(
              av[kk], bv[tn][kk], acc[m][tn], 0, 0, 0);
    }
    __builtin_amdgcn_s_setprio(0);
  }

  // Epilogue: tn-pairs (0,1) and (2,3) hold (k,p) for the same 16 h-cols.
  // D layout: col=lane&15, row=q*4+i.
  #pragma unroll
  for (int tp = 0; tp < 2; ++tp) {
    const int ncol = nTile + wn * 64 + tp * 32;      // k-column base
    const int h = ((ncol >> 5) << 4) + mn;
    const float bzc = bz[h], bhc = bh[h];
    #pragma unroll
    for (int m = 0; m < 8; ++m) {
      const int row0 = mTile + wm * 128 + m * 16 + q * 4;
      #pragma unroll
      for (int i = 0; i < 4; ++i) {
        float kv = acc[m][2 * tp][i] + bzc;
        float pv = acc[m][2 * tp + 1][i] + bhc;
        float c = __builtin_amdgcn_rcpf(1.0f + __expf(kv));  // sigmoid(-k)
        float v = (1.0f - c) * gfun(pv);                      // sigmoid(k)*g(p)
        union { _Float16 h2[2]; uint32_t u; } pk;
        pk.h2[0] = (_Float16)c; pk.h2[1] = (_Float16)v;
        cv[(size_t)(row0 + i) * H_ + h] = pk.u;
      }
    }
  }
}

// ---------------- scan pass 1: per-chunk (C, V) composition ----------------
__global__ __launch_bounds__(256) void scan_chunk_kernel(
    const uint32_t* __restrict__ cv, float4* __restrict__ Cc,
    float4* __restrict__ Vc) {
  const int tid = threadIdx.x;                 // channels tid*4..tid*4+3
  const int nc = blockIdx.x, b = blockIdx.y;
  const uint4* cv4 = (const uint4*)cv;
  size_t base = (size_t)(b * S_ + nc * L_) * (H_ / 4) + tid;
  float C[4] = {1.f, 1.f, 1.f, 1.f};
  float V[4] = {0.f, 0.f, 0.f, 0.f};
  #pragma unroll 4
  for (int t = 0; t < L_; t++) {
    uint4 w = cv4[base + (size_t)t * (H_ / 4)];
    float c, v;
    unpack_cv(w.x, c, v); C[0] *= c; V[0] = c * V[0] + v;
    unpack_cv(w.y, c, v); C[1] *= c; V[1] = c * V[1] + v;
    unpack_cv(w.z, c, v); C[2] *= c; V[2] = c * V[2] + v;
    unpack_cv(w.w, c, v); C[3] *= c; V[3] = c * V[3] + v;
  }
  size_t o = (size_t)(b * NC_ + nc) * (H_ / 4) + tid;
  Cc[o] = (float4){C[0], C[1], C[2], C[3]};
  Vc[o] = (float4){V[0], V[1], V[2], V[3]};
}

// ---------------- scan pass 2: apply with inline carry-in prefix ----------------
__global__ __launch_bounds__(256) void scan_apply_kernel(
    const uint32_t* __restrict__ cv, const float4* __restrict__ Cc,
    const float4* __restrict__ Vc, const float* __restrict__ h0,
    float4* __restrict__ out) {
  const int tid = threadIdx.x;
  const int nc = blockIdx.x, b = blockIdx.y;
  const uint4* cv4 = (const uint4*)cv;

  // Carry-in: H = g(h0), then compose chunk states 0..nc-1 (small, L2-hot).
  float Hr[4];
  #pragma unroll
  for (int j = 0; j < 4; j++) Hr[j] = gfun(h0[(size_t)b * H_ + tid * 4 + j]);
  #pragma unroll 4
  for (int j = 0; j < nc; j++) {
    size_t idx = (size_t)(b * NC_ + j) * (H_ / 4) + tid;
    float4 Cq = Cc[idx], Vq = Vc[idx];
    Hr[0] = Cq.x * Hr[0] + Vq.x;
    Hr[1] = Cq.y * Hr[1] + Vq.y;
    Hr[2] = Cq.z * Hr[2] + Vq.z;
    Hr[3] = Cq.w * Hr[3] + Vq.w;
  }

  size_t base = (size_t)(b * S_ + nc * L_) * (H_ / 4) + tid;
  #pragma unroll 4
  for (int t = 0; t < L_; t++) {
    size_t idx = base + (size_t)t * (H_ / 4);
    uint4 w = cv4[idx];
    float c, v;
    unpack_cv(w.x, c, v); Hr[0] = c * Hr[0] + v;
    unpack_cv(w.y, c, v); Hr[1] = c * Hr[1] + v;
    unpack_cv(w.z, c, v); Hr[2] = c * Hr[2] + v;
    unpack_cv(w.w, c, v); Hr[3] = c * Hr[3] + v;
    out[idx] = (float4){Hr[0], Hr[1], Hr[2], Hr[3]};
  }
}

extern "C" void kernel_launch(void* const* d_in, const int* in_sizes, int n_in,
                              void* d_out, int out_size, void* d_ws, size_t ws_size,
                              hipStream_t stream) {
  const float* x  = (const float*)d_in[0];
  const float* h0 = (const float*)d_in[1];
  const float* Wz = (const float*)d_in[2];
  const float* bz = (const float*)d_in[3];
  const float* Wh = (const float*)d_in[4];
  const float* bh = (const float*)d_in[5];
  float* out = (float*)d_out;

  // Workspace layout (~202 MB): xb is dead after the GEMM; scan chunk-state
  // buffers alias its region.
  char* ws = (char*)d_ws;
  uint16_t* xb  = (uint16_t*)ws; ws += (size_t)M_ * D_ * 2;      // 64 MB
  uint16_t* Wcb = (uint16_t*)ws; ws += (size_t)NT_ * D_ * 2;     // 4 MB
  uint32_t* cvb = (uint32_t*)ws; ws += (size_t)M_ * H_ * 4;      // 134 MB
  char* alias = (char*)xb;
  float* Cc  = (float*)alias; alias += (size_t)B_ * NC_ * H_ * 4;  // 2 MB
  float* Vc  = (float*)alias; alias += (size_t)B_ * NC_ * H_ * 4;  // 2 MB

  // 1) convert x -> bf16; interleave Wz/Wh -> Wc (2048x1024 bf16)
  cvt_all_kernel<<<dim3(2048), 256, 0, stream>>>(x, Wz, Wh, xb, Wcb);

  // 2) 256x256-tile phase-split GEMM + activation -> packed (c,v) fp16 pairs
  fused_gemm_kernel<<<dim3((NT_ / 256) * (M_ / 256)), 512, 0, stream>>>(
      xb, Wcb, bz, bh, cvb);

  // 3-4) chunked linear scan
  scan_chunk_kernel<<<dim3(NC_, B_), 256, 0, stream>>>(cvb, (float4*)Cc, (float4*)Vc);
  scan_apply_kernel<<<dim3(NC_, B_), 256, 0, stream>>>(
      cvb, (const float4*)Cc, (const float4*)Vc, h0, (float4*)out);
}

// Round 4
// 442.214 us; speedup vs baseline: 1.0104x; 1.0104x over previous
//
#include <hip/hip_runtime.h>
#include <cstdint>
#include <cstddef>

// Problem dims (fixed by setup_inputs)
#define B_  8
#define S_  4096
#define D_  1024
#define H_  1024
#define M_  (B_*S_)          // 32768 GEMM rows
#define NT_ 2048             // interleaved N (k,p pairs at 16-col granularity)
#define NC_ 64               // scan chunks
#define L_  (S_/NC_)         // 64 steps per chunk

typedef __bf16 bf16x8 __attribute__((ext_vector_type(8)));
typedef float  f32x4  __attribute__((ext_vector_type(4)));
typedef uint16_t u16x8 __attribute__((ext_vector_type(8)));

__device__ __forceinline__ uint16_t f2bf(float f) {
  union { float f; uint32_t u; } v; v.f = f;
  uint32_t u = v.u;
  u += 0x7FFFu + ((u >> 16) & 1u);   // RNE
  return (uint16_t)(u >> 16);
}
__device__ __forceinline__ float gfun(float x) {
  // g(x) = x+0.5 if x>=0 else sigmoid(x)
  return x >= 0.0f ? x + 0.5f
                   : __builtin_amdgcn_rcpf(1.0f + __expf(-x));
}
__device__ __forceinline__ void unpack_cv(uint32_t u, float& c, float& v) {
  union { uint32_t u; _Float16 h[2]; } p; p.u = u;
  c = (float)p.h[0]; v = (float)p.h[1];
}

// ---------------- fused fp32 -> bf16 convert for x, and Wz/Wh -> interleaved Wc --
// Wc row layout: group g (0..63): rows 32g..32g+15 = Wz rows 16g..16g+15,
//                                 rows 32g+16..32g+31 = Wh rows 16g..16g+15.
#define X8_  (M_ * D_ / 8)
#define W8_  (H_ * D_ / 8)
#define TOT8_ (X8_ + 2 * W8_)
__global__ __launch_bounds__(256) void cvt_all_kernel(
    const float* __restrict__ x, const float* __restrict__ Wz,
    const float* __restrict__ Wh, uint16_t* __restrict__ xb,
    uint16_t* __restrict__ Wc) {
  int stride = gridDim.x * 256;
  for (int u = blockIdx.x * 256 + threadIdx.x; u < TOT8_; u += stride) {
    const float* src; uint16_t* dst;
    if (u < X8_) {
      src = x + (size_t)u * 8; dst = xb + (size_t)u * 8;
    } else if (u < X8_ + W8_) {
      int v = u - X8_;
      int r = v >> 7, c = v & 127;
      int row = ((r >> 4) << 5) | (r & 15);
      src = Wz + (size_t)v * 8;
      dst = Wc + (size_t)row * D_ + c * 8;
    } else {
      int v = u - X8_ - W8_;
      int r = v >> 7, c = v & 127;
      int row = ((r >> 4) << 5) | 16 | (r & 15);
      src = Wh + (size_t)v * 8;
      dst = Wc + (size_t)row * D_ + c * 8;
    }
    float4 a = ((const float4*)src)[0], b = ((const float4*)src)[1];
    u16x8 o;
    o[0] = f2bf(a.x); o[1] = f2bf(a.y); o[2] = f2bf(a.z); o[3] = f2bf(a.w);
    o[4] = f2bf(b.x); o[5] = f2bf(b.y); o[6] = f2bf(b.z); o[7] = f2bf(b.w);
    *(u16x8*)dst = o;
  }
}

// ---------------- 256x256-tile 8-wave phase-split GEMM + activation epilogue ----
// C = A(32768x1024) * Wc^T(2048x1024). 8 waves as 2(M)x4(N); per-wave 128x64.
// 4 phases per K-tile (BK=64): phase p computes m-pair {2p,2p+1} (16 MFMA).
// ONE barrier per phase (after the optional counted vmcnt); compiler-managed
// lgkmcnt between ds_reads and MFMAs. vmcnt ledger: see comments at loop.
// Last K-tile peeled with a vmcnt(0) drain (round-1 lesson: counted-N breaks
// on the no-stage tail iteration).
// Epilogue: tn even = k-frag, tn odd = p-frag for the SAME h columns; in
// addition to the packed (c,v) store, each block composes its 4 aligned
// 64-step scan chunks IN REGISTERS (from the fp16-ROUNDED c,v — bit-identical
// to the old scan_chunk math) and writes chunk states S[b][nc][h]. This
// replaces the scan_chunk kernel's full 134 MB re-read of cv.
#define BK 64
__global__ __launch_bounds__(512, 2)
void fused_gemm_kernel(const uint16_t* __restrict__ A,
                       const uint16_t* __restrict__ Wc,
                       const float* __restrict__ bz,
                       const float* __restrict__ bh,
                       uint32_t* __restrict__ cv,
                       float* __restrict__ Sc,
                       float* __restrict__ Sv) {
  __shared__ __attribute__((aligned(16))) uint16_t sA[2][256 * BK];  // 2 x 32 KB
  __shared__ __attribute__((aligned(16))) uint16_t sB[2][256 * BK];  // 2 x 32 KB

  const int tid  = threadIdx.x;
  const int lane = tid & 63;
  const int wave = tid >> 6;
  const int wm = wave >> 2;        // 0..1  (M half)
  const int wn = wave & 3;         // 0..3  (N quarter)
  const int q  = lane >> 4;
  const int mn = lane & 15;

  // Bijective XCD swizzle: nwg=1024 (%8==0). Each XCD owns 16 contiguous
  // A row-panels (bx fastest within an XCD -> A panel stays L2-hot).
  const int bid  = blockIdx.x;
  const int tile = (bid & 7) * 128 + (bid >> 3);
  const int mTile = (tile >> 3) * 256;
  const int nTile = (tile & 7) * 256;

  // Staging addresses: load-unit L = 64 rows x 64 cols (8 KB = 512 thr x 16 B).
  // LDS dest is linear (tid*16 B); source col-unit pre-swizzled by cu^(r&7).
  const int rl = tid >> 3;         // 0..63 row within unit
  const int cu = tid & 7;          // 16B col-unit
  const int sw = cu ^ (rl & 7);
  const uint16_t* aSrc[4];
  const uint16_t* bSrc[4];
  #pragma unroll
  for (int L = 0; L < 4; L++) {
    aSrc[L] = A  + (size_t)(mTile + L * 64 + rl) * D_ + sw * 8;
    bSrc[L] = Wc + (size_t)(nTile + L * 64 + rl) * D_ + sw * 8;
  }
  const int ldsSlot = tid * 8;     // element offset inside the 4096-elem unit

  // Read-side bases (elements; row stride 64). r&7 == mn&7 for all fragments.
  const int swr = mn & 7;
  const int aBase = (wm * 128 + mn) * 64;
  const int bBase = (wn * 64  + mn) * 64;
  int koff[2];
  #pragma unroll
  for (int kk = 0; kk < 2; kk++) koff[kk] = ((kk * 4 + q) ^ swr) * 8;

#define STAGE_A(buf, kt, L)                                                    \
  __builtin_amdgcn_global_load_lds(                                            \
      (const __attribute__((address_space(1))) void*)(aSrc[L] + (kt) * BK),    \
      (__attribute__((address_space(3))) void*)&sA[buf][(L) * 4096 + ldsSlot], \
      16, 0, 0)
#define STAGE_B(buf, kt, L)                                                    \
  __builtin_amdgcn_global_load_lds(                                            \
      (const __attribute__((address_space(1))) void*)(bSrc[L] + (kt) * BK),    \
      (__attribute__((address_space(3))) void*)&sB[buf][(L) * 4096 + ldsSlot], \
      16, 0, 0)

  f32x4 acc[8][4] = {};

  // Prologue: tile 0 and tile 1, stream order A0,A2,B0,B1,B2,B3,A1,A3 each.
  STAGE_A(0, 0, 0); STAGE_A(0, 0, 2);
  STAGE_B(0, 0, 0); STAGE_B(0, 0, 1); STAGE_B(0, 0, 2); STAGE_B(0, 0, 3);
  STAGE_A(0, 0, 1); STAGE_A(0, 0, 3);
  STAGE_A(1, 1, 0); STAGE_A(1, 1, 2);
  STAGE_B(1, 1, 0); STAGE_B(1, 1, 1); STAGE_B(1, 1, 2); STAGE_B(1, 1, 3);
  STAGE_A(1, 1, 1); STAGE_A(1, 1, 3);
  asm volatile("s_waitcnt vmcnt(8)" ::: "memory");   // tile 0 fully landed
  __builtin_amdgcn_s_barrier();
  __builtin_amdgcn_sched_barrier(0);

  // Main loop over tiles 0..14 (tile 15 peeled).  Per-wave vmcnt ledger:
  //   entering p0: 2 outstanding (A1,A3 of tile t, issued at t-1 p3)
  //   p0 +2 (A0,A2 t+1) =4 | p1 +2 (B0,B1 t+1) =6, vmcnt(4) -> t's A1,A3 landed
  //   p2 +2 (B2,B3 t+1) =6 | p3 +2 (A1,A3 t+1) =8, vmcnt(2) -> t+1's first 6 landed
  #pragma unroll 2
  for (int t = 0; t < D_ / BK - 1; ++t) {
    const int curb = t & 1, nxtb = curb ^ 1;
    const uint16_t* sAc = sA[curb];
    const uint16_t* sBc = sB[curb];
    const bool doStage = (t >= 1);
    const int kn = t + 1;

    bf16x8 bv[4][2];

    #pragma unroll
    for (int p = 0; p < 4; ++p) {
      // ds-reads for this phase (compiler inserts counted lgkmcnt before the
      // consuming MFMAs -> reads drain under the MFMA cluster).
      if (p == 0) {
        #pragma unroll
        for (int tn = 0; tn < 4; tn++)
          #pragma unroll
          for (int kk = 0; kk < 2; kk++)
            bv[tn][kk] = *(const bf16x8*)&sBc[bBase + tn * 1024 + koff[kk]];
      }
      bf16x8 av[2][2];
      #pragma unroll
      for (int mi = 0; mi < 2; mi++)
        #pragma unroll
        for (int kk = 0; kk < 2; kk++)
          av[mi][kk] =
              *(const bf16x8*)&sAc[aBase + (2 * p + mi) * 1024 + koff[kk]];

      // Stage tile t+1 into the other buffer, consumption-lead order.
      if (doStage) {
        if (p == 0) { STAGE_A(nxtb, kn, 0); STAGE_A(nxtb, kn, 2); }
        if (p == 1) { STAGE_B(nxtb, kn, 0); STAGE_B(nxtb, kn, 1); }
        if (p == 2) { STAGE_B(nxtb, kn, 2); STAGE_B(nxtb, kn, 3); }
        if (p == 3) { STAGE_A(nxtb, kn, 1); STAGE_A(nxtb, kn, 3); }
      }

      __builtin_amdgcn_s_setprio(1);
      #pragma unroll
      for (int mi = 0; mi < 2; mi++)
        #pragma unroll
        for (int tn = 0; tn < 4; tn++)
          #pragma unroll
          for (int kk = 0; kk < 2; kk++)
            acc[2 * p + mi][tn] = __builtin_amdgcn_mfma_f32_16x16x32_bf16(
                av[mi][kk], bv[tn][kk], acc[2 * p + mi][tn], 0, 0, 0);
      __builtin_amdgcn_s_setprio(0);

      // Counted waits (never 0), BEFORE the phase barrier so the per-wave
      // landing confirmation becomes workgroup-global.
      if (p == 1) asm volatile("s_waitcnt vmcnt(4)" ::: "memory");
      if (p == 3) asm volatile("s_waitcnt vmcnt(2)" ::: "memory");
      __builtin_amdgcn_s_barrier();
      __builtin_amdgcn_sched_barrier(0);
    }
  }
#undef STAGE_A
#undef STAGE_B

  // ---- Peeled tail: tile 15 (buffer 1). Drain the last 2 in-flight loads,
  // barrier so ALL waves' contributions have landed, then plain reads + MFMA.
  asm volatile("s_waitcnt vmcnt(0)" ::: "memory");
  __builtin_amdgcn_s_barrier();
  __builtin_amdgcn_sched_barrier(0);
  {
    const uint16_t* sAc = sA[1];
    const uint16_t* sBc = sB[1];
    bf16x8 bv[4][2];
    #pragma unroll
    for (int tn = 0; tn < 4; tn++)
      #pragma unroll
      for (int kk = 0; kk < 2; kk++)
        bv[tn][kk] = *(const bf16x8*)&sBc[bBase + tn * 1024 + koff[kk]];
    __builtin_amdgcn_s_setprio(1);
    #pragma unroll
    for (int m = 0; m < 8; m++) {
      bf16x8 av[2];
      #pragma unroll
      for (int kk = 0; kk < 2; kk++)
        av[kk] = *(const bf16x8*)&sAc[aBase + m * 1024 + koff[kk]];
      #pragma unroll
      for (int tn = 0; tn < 4; tn++)
        #pragma unroll
        for (int kk = 0; kk < 2; kk++)
          acc[m][tn] = __builtin_amdgcn_mfma_f32_16x16x32_bf16(
              av[kk], bv[tn][kk], acc[m][tn], 0, 0, 0);
    }
    __builtin_amdgcn_s_setprio(0);
  }

  // Epilogue. D layout: col=lane&15, row=q*4+i. tn-pairs (0,1),(2,3) hold
  // (k,p) for the same 16 h-cols (lane-local).
  // Scan-chunk fusion: the block's rows mTile..mTile+255 are 4 aligned 64-step
  // chunks of batch b. For fixed h (= fixed wn,tp,mn), wave wm covers chunks
  // {2wm, 2wm+1}; rows within a chunk are ordered lexicographically by
  // (m&3, q, i). Compose: in-lane over i (4 steps), across q via 2 ordered
  // shfl_xor steps (16 steps), across m&3 in-lane (64 steps), then q==0
  // lanes write S[b][nc][h]. Compose uses the fp16-ROUNDED (c,v) so it is
  // bit-identical to the old scan_chunk kernel's math.
  const int bIdx = mTile >> 12;                 // batch index
  const int nc0  = (mTile & (S_ - 1)) >> 6;     // first 64-chunk of this tile
  #pragma unroll
  for (int tp = 0; tp < 2; ++tp) {
    const int ncol = nTile + wn * 64 + tp * 32;      // k-column base
    const int h = ((ncol >> 5) << 4) + mn;
    const float bzc = bz[h], bhc = bh[h];
    float Cr = 1.0f, Vr = 0.0f;                      // running 64-step state
    #pragma unroll
    for (int m = 0; m < 8; ++m) {
      const int row0 = mTile + wm * 128 + m * 16 + q * 4;
      float Ct = 1.0f, Vt = 0.0f;                    // 4-step in-lane state
      #pragma unroll
      for (int i = 0; i < 4; ++i) {
        float kv = acc[m][2 * tp][i] + bzc;
        float pv = acc[m][2 * tp + 1][i] + bhc;
        float c = __builtin_amdgcn_rcpf(1.0f + __expf(kv));  // sigmoid(-k)
        float v = (1.0f - c) * gfun(pv);                      // sigmoid(k)*g(p)
        union { _Float16 h2[2]; uint32_t u; } pk;
        pk.h2[0] = (_Float16)c; pk.h2[1] = (_Float16)v;
        cv[(size_t)(row0 + i) * H_ + h] = pk.u;
        float cr_ = (float)pk.h2[0], vr_ = (float)pk.h2[1];   // rounded values
        Vt = cr_ * Vt + vr_;
        Ct = Ct * cr_;
      }
      // q-compose, ordered (a-before-b: C=Ca*Cb, V=Cb*Va+Vb).
      {
        float Cp = __shfl_xor(Ct, 16), Vp = __shfl_xor(Vt, 16);
        Vt = (q & 1) ? (Ct * Vp + Vt) : (Cp * Vt + Vp);
        Ct = Ct * Cp;
        Cp = __shfl_xor(Ct, 32); Vp = __shfl_xor(Vt, 32);
        Vt = (q & 2) ? (Ct * Vp + Vt) : (Cp * Vt + Vp);
        Ct = Ct * Cp;
      }
      if ((m & 3) == 0) { Cr = Ct; Vr = Vt; }
      else             { Vr = Ct * Vr + Vt; Cr = Cr * Ct; }
      if ((m & 3) == 3) {
        if (q == 0) {
          const int nc = nc0 + wm * 2 + (m >> 2);
          const size_t sidx = ((size_t)(bIdx * NC_ + nc) << 10) + h;
          Sc[sidx] = Cr;
          Sv[sidx] = Vr;
        }
        Cr = 1.0f; Vr = 0.0f;
      }
    }
  }
}

// ---------------- prefix pass: raw chunk states -> exclusive prefix states ----
// Thread per (b,h): P_excl[b][nc] = S[b][0] ∘ ... ∘ S[b][nc-1] (identity at 0).
// 8 MB total traffic; replaces scan_chunk's 138 MB pass.
__global__ __launch_bounds__(256) void prefix_kernel(
    const float* __restrict__ Sc, const float* __restrict__ Sv,
    float* __restrict__ Pc, float* __restrict__ Pv) {
  const int u = blockIdx.x * 256 + threadIdx.x;  // 8192 threads
  const int b = u >> 10, h = u & 1023;
  float C = 1.0f, V = 0.0f;
  #pragma unroll 4
  for (int nc = 0; nc < NC_; nc++) {
    const size_t idx = ((size_t)(b * NC_ + nc) << 10) + h;
    Pc[idx] = C; Pv[idx] = V;
    const float sc = Sc[idx], sv = Sv[idx];
    V = sc * V + sv;     // existing ∘ S
    C = C * sc;
  }
}

// ---------------- scan apply: single-compose carry-in + 64-step chunk ----------
__global__ __launch_bounds__(256) void scan_apply_kernel(
    const uint32_t* __restrict__ cv, const float4* __restrict__ Pc,
    const float4* __restrict__ Pv, const float* __restrict__ h0,
    float4* __restrict__ out) {
  const int tid = threadIdx.x;
  const int nc = blockIdx.x, b = blockIdx.y;
  const uint4* cv4 = (const uint4*)cv;

  // Carry-in: H = g(h0) then ONE affine compose with the exclusive prefix.
  float Hr[4];
  #pragma unroll
  for (int j = 0; j < 4; j++) Hr[j] = gfun(h0[(size_t)b * H_ + tid * 4 + j]);
  {
    const size_t pidx = (size_t)(b * NC_ + nc) * (H_ / 4) + tid;
    const float4 Cq = Pc[pidx], Vq = Pv[pidx];
    Hr[0] = Cq.x * Hr[0] + Vq.x;
    Hr[1] = Cq.y * Hr[1] + Vq.y;
    Hr[2] = Cq.z * Hr[2] + Vq.z;
    Hr[3] = Cq.w * Hr[3] + Vq.w;
  }

  size_t base = (size_t)(b * S_ + nc * L_) * (H_ / 4) + tid;
  #pragma unroll 4
  for (int t = 0; t < L_; t++) {
    size_t idx = base + (size_t)t * (H_ / 4);
    uint4 w = cv4[idx];
    float c, v;
    unpack_cv(w.x, c, v); Hr[0] = c * Hr[0] + v;
    unpack_cv(w.y, c, v); Hr[1] = c * Hr[1] + v;
    unpack_cv(w.z, c, v); Hr[2] = c * Hr[2] + v;
    unpack_cv(w.w, c, v); Hr[3] = c * Hr[3] + v;
    out[idx] = (float4){Hr[0], Hr[1], Hr[2], Hr[3]};
  }
}

extern "C" void kernel_launch(void* const* d_in, const int* in_sizes, int n_in,
                              void* d_out, int out_size, void* d_ws, size_t ws_size,
                              hipStream_t stream) {
  const float* x  = (const float*)d_in[0];
  const float* h0 = (const float*)d_in[1];
  const float* Wz = (const float*)d_in[2];
  const float* bz = (const float*)d_in[3];
  const float* Wh = (const float*)d_in[4];
  const float* bh = (const float*)d_in[5];
  float* out = (float*)d_out;

  // Workspace layout (~202 MB, unchanged footprint):
  //   xb is dead after the GEMM; prefix-state buffers alias its region.
  // Raw chunk states Sc/Sv live in the first 4 MB of d_out (scratch until
  // scan_apply runs; disjoint from ws).
  char* ws = (char*)d_ws;
  uint16_t* xb  = (uint16_t*)ws; ws += (size_t)M_ * D_ * 2;      // 64 MB
  uint16_t* Wcb = (uint16_t*)ws; ws += (size_t)NT_ * D_ * 2;     // 4 MB
  uint32_t* cvb = (uint32_t*)ws; ws += (size_t)M_ * H_ * 4;      // 134 MB
  char* alias = (char*)xb;
  float* Pc = (float*)alias; alias += (size_t)B_ * NC_ * H_ * 4;   // 2 MB
  float* Pv = (float*)alias; alias += (size_t)B_ * NC_ * H_ * 4;   // 2 MB
  float* Sc = out;                                                 // 2 MB scratch
  float* Sv = out + (size_t)B_ * NC_ * H_;                         // 2 MB scratch

  // 1) convert x -> bf16; interleave Wz/Wh -> Wc (2048x1024 bf16)
  cvt_all_kernel<<<dim3(2048), 256, 0, stream>>>(x, Wz, Wh, xb, Wcb);

  // 2) GEMM + activation -> packed (c,v); also emits 64-step chunk states
  fused_gemm_kernel<<<dim3((NT_ / 256) * (M_ / 256)), 512, 0, stream>>>(
      xb, Wcb, bz, bh, cvb, Sc, Sv);

  // 3) tiny prefix pass over chunk states (8 MB traffic)
  prefix_kernel<<<dim3(B_ * H_ / 256), 256, 0, stream>>>(Sc, Sv, Pc, Pv);

  // 4) apply with single-compose carry-in
  scan_apply_kernel<<<dim3(NC_, B_), 256, 0, stream>>>(
      cvb, (const float4*)Pc, (const float4*)Pv, h0, (float4*)out);
}

// Round 5
// 435.680 us; speedup vs baseline: 1.0256x; 1.0150x over previous
//
#include <hip/hip_runtime.h>
#include <cstdint>
#include <cstddef>

// Problem dims (fixed by setup_inputs)
#define B_  8
#define S_  4096
#define D_  1024
#define H_  1024
#define M_  (B_*S_)          // 32768 GEMM rows
#define NT_ 2048             // interleaved N (k,p pairs at 16-col granularity)
#define NC_ 64               // scan chunks
#define L_  (S_/NC_)         // 64 steps per chunk

typedef __bf16 bf16x8 __attribute__((ext_vector_type(8)));
typedef float  f32x4  __attribute__((ext_vector_type(4)));
typedef uint16_t u16x8 __attribute__((ext_vector_type(8)));

__device__ __forceinline__ uint16_t f2bf(float f) {
  union { float f; uint32_t u; } v; v.f = f;
  uint32_t u = v.u;
  u += 0x7FFFu + ((u >> 16) & 1u);   // RNE
  return (uint16_t)(u >> 16);
}
__device__ __forceinline__ float gfun(float x) {
  // g(x) = x+0.5 if x>=0 else sigmoid(x)
  return x >= 0.0f ? x + 0.5f
                   : __builtin_amdgcn_rcpf(1.0f + __expf(-x));
}
__device__ __forceinline__ void unpack_cv(uint32_t u, float& c, float& v) {
  union { uint32_t u; _Float16 h[2]; } p; p.u = u;
  c = (float)p.h[0]; v = (float)p.h[1];
}

// ---------------- fused fp32 -> bf16 convert for x, and Wz/Wh -> interleaved Wc --
// Wc row layout: group g (0..63): rows 32g..32g+15 = Wz rows 16g..16g+15,
//                                 rows 32g+16..32g+31 = Wh rows 16g..16g+15.
#define X8_  (M_ * D_ / 8)
#define W8_  (H_ * D_ / 8)
#define TOT8_ (X8_ + 2 * W8_)
__global__ __launch_bounds__(256) void cvt_all_kernel(
    const float* __restrict__ x, const float* __restrict__ Wz,
    const float* __restrict__ Wh, uint16_t* __restrict__ xb,
    uint16_t* __restrict__ Wc) {
  int stride = gridDim.x * 256;
  for (int u = blockIdx.x * 256 + threadIdx.x; u < TOT8_; u += stride) {
    const float* src; uint16_t* dst;
    if (u < X8_) {
      src = x + (size_t)u * 8; dst = xb + (size_t)u * 8;
    } else if (u < X8_ + W8_) {
      int v = u - X8_;
      int r = v >> 7, c = v & 127;
      int row = ((r >> 4) << 5) | (r & 15);
      src = Wz + (size_t)v * 8;
      dst = Wc + (size_t)row * D_ + c * 8;
    } else {
      int v = u - X8_ - W8_;
      int r = v >> 7, c = v & 127;
      int row = ((r >> 4) << 5) | 16 | (r & 15);
      src = Wh + (size_t)v * 8;
      dst = Wc + (size_t)row * D_ + c * 8;
    }
    float4 a = ((const float4*)src)[0], b = ((const float4*)src)[1];
    u16x8 o;
    o[0] = f2bf(a.x); o[1] = f2bf(a.y); o[2] = f2bf(a.z); o[3] = f2bf(a.w);
    o[4] = f2bf(b.x); o[5] = f2bf(b.y); o[6] = f2bf(b.z); o[7] = f2bf(b.w);
    *(u16x8*)dst = o;
  }
}

// ---------------- 256x256-tile 8-wave GEMM, 2 syncs per K-tile ----------------
// C = A(32768x1024) * Wc^T(2048x1024). 8 waves as 2(M)x4(N); per-wave 128x64.
// K-tile (BK=64) = 4 MFMA clusters (m-pairs), free-running between TWO sync
// points only:
//   mid  (after clusters 0,1): vmcnt(4)+s_barrier — globalizes landing of this
//        tile's A1/A3 units (still in flight at tile start), which clusters
//        2,3 read (rows 64..127 of each wave half).
//   end  (after clusters 2,3): vmcnt(2)+s_barrier — globalizes t+1's first 6
//        units; leaves A1/A3(t+1) in flight (never drains to 0 in the loop).
// Each sync is ONE asm block with "memory" clobber: no LDS read can slip
// between the vmcnt and the barrier (it would see other waves' unlanded
// slices). Between syncs, waves drift: one wave's ds_reads overlap another's
// setprio'd MFMA cluster — the cross-wave overlap the old 4-barrier lockstep
// prevented (rounds 2/3: MfmaUtil pinned at 39%).
// Per-wave vmcnt ledger (stage order A0,A2 | B0,B1 | B2,B3 | A1,A3):
//   tile start: 2 outstanding (A1,A3 of t). +A0,A2 = 4, +B0,B1 = 6;
//   mid vmcnt(4) -> A1,A3(t) landed. +B2,B3 = 6, +A1,A3 = 8;
//   end vmcnt(2) -> all t+1 except A1,A3(t+1) landed. Invariant restored.
// Last K-tile peeled with a vmcnt(0) drain (round-1 lesson: counted-N breaks
// on the no-stage tail iteration).
// Epilogue: tn-pairs (0,1),(2,3) = (k,p) for h and h+16; tp0/tp1 interleaved
// per row so both 64B halves of each 128B cv line are written adjacently
// (WRITE_SIZE showed ~50 MB partial-line amplification). Also composes the
// block's 4 aligned 64-step scan chunks in registers (fp16-rounded (c,v),
// bit-identical to the old scan_chunk math) -> chunk states S[b][nc][h].
#define BK 64
__global__ __launch_bounds__(512, 2)
void fused_gemm_kernel(const uint16_t* __restrict__ A,
                       const uint16_t* __restrict__ Wc,
                       const float* __restrict__ bz,
                       const float* __restrict__ bh,
                       uint32_t* __restrict__ cv,
                       float* __restrict__ Sc,
                       float* __restrict__ Sv) {
  __shared__ __attribute__((aligned(16))) uint16_t sA[2][256 * BK];  // 2 x 32 KB
  __shared__ __attribute__((aligned(16))) uint16_t sB[2][256 * BK];  // 2 x 32 KB

  const int tid  = threadIdx.x;
  const int lane = tid & 63;
  const int wave = tid >> 6;
  const int wm = wave >> 2;        // 0..1  (M half)
  const int wn = wave & 3;         // 0..3  (N quarter)
  const int q  = lane >> 4;
  const int mn = lane & 15;

  // Bijective XCD swizzle: nwg=1024 (%8==0). Each XCD owns 16 contiguous
  // A row-panels (A fetched exactly once from HBM — FETCH confirms).
  const int bid  = blockIdx.x;
  const int tile = (bid & 7) * 128 + (bid >> 3);
  const int mTile = (tile >> 3) * 256;
  const int nTile = (tile & 7) * 256;

  // Staging addresses: load-unit L = 64 rows x 64 cols (8 KB = 512 thr x 16 B).
  // LDS dest is linear (tid*16 B); source col-unit pre-swizzled by cu^(r&7).
  const int rl = tid >> 3;         // 0..63 row within unit
  const int cu = tid & 7;          // 16B col-unit
  const int sw = cu ^ (rl & 7);
  const uint16_t* aSrc[4];
  const uint16_t* bSrc[4];
  #pragma unroll
  for (int L = 0; L < 4; L++) {
    aSrc[L] = A  + (size_t)(mTile + L * 64 + rl) * D_ + sw * 8;
    bSrc[L] = Wc + (size_t)(nTile + L * 64 + rl) * D_ + sw * 8;
  }
  const int ldsSlot = tid * 8;     // element offset inside the 4096-elem unit

  // Read-side bases (elements; row stride 64). r&7 == mn&7 for all fragments.
  const int swr = mn & 7;
  const int aBase = (wm * 128 + mn) * 64;
  const int bBase = (wn * 64  + mn) * 64;
  int koff[2];
  #pragma unroll
  for (int kk = 0; kk < 2; kk++) koff[kk] = ((kk * 4 + q) ^ swr) * 8;

#define STAGE_A(buf, kt, L)                                                    \
  __builtin_amdgcn_global_load_lds(                                            \
      (const __attribute__((address_space(1))) void*)(aSrc[L] + (kt) * BK),    \
      (__attribute__((address_space(3))) void*)&sA[buf][(L) * 4096 + ldsSlot], \
      16, 0, 0)
#define STAGE_B(buf, kt, L)                                                    \
  __builtin_amdgcn_global_load_lds(                                            \
      (const __attribute__((address_space(1))) void*)(bSrc[L] + (kt) * BK),    \
      (__attribute__((address_space(3))) void*)&sB[buf][(L) * 4096 + ldsSlot], \
      16, 0, 0)

// One MFMA cluster: m-pair {2mp, 2mp+1}; kk-outer so kk0 MFMAs can start
// while kk1 ds_reads drain (per-acc accumulation order unchanged: kk0, kk1).
#define CLUSTER(mp)                                                            \
  do {                                                                         \
    bf16x8 av[2][2];                                                           \
    _Pragma("unroll")                                                          \
    for (int kk = 0; kk < 2; kk++)                                             \
      _Pragma("unroll")                                                        \
      for (int mi = 0; mi < 2; mi++)                                           \
        av[mi][kk] =                                                           \
            *(const bf16x8*)&sAc[aBase + (2 * (mp) + mi) * 1024 + koff[kk]];   \
    __builtin_amdgcn_s_setprio(1);                                             \
    _Pragma("unroll")                                                          \
    for (int kk = 0; kk < 2; kk++)                                             \
      _Pragma("unroll")                                                        \
      for (int mi = 0; mi < 2; mi++)                                           \
        _Pragma("unroll")                                                      \
        for (int tn = 0; tn < 4; tn++)                                         \
          acc[2 * (mp) + mi][tn] = __builtin_amdgcn_mfma_f32_16x16x32_bf16(    \
              av[mi][kk], bv[tn][kk], acc[2 * (mp) + mi][tn], 0, 0, 0);        \
    __builtin_amdgcn_s_setprio(0);                                             \
  } while (0)

  f32x4 acc[8][4] = {};

  // Prologue: tile 0 and tile 1, stream order A0,A2,B0,B1,B2,B3,A1,A3 each.
  STAGE_A(0, 0, 0); STAGE_A(0, 0, 2);
  STAGE_B(0, 0, 0); STAGE_B(0, 0, 1); STAGE_B(0, 0, 2); STAGE_B(0, 0, 3);
  STAGE_A(0, 0, 1); STAGE_A(0, 0, 3);
  STAGE_A(1, 1, 0); STAGE_A(1, 1, 2);
  STAGE_B(1, 1, 0); STAGE_B(1, 1, 1); STAGE_B(1, 1, 2); STAGE_B(1, 1, 3);
  STAGE_A(1, 1, 1); STAGE_A(1, 1, 3);
  asm volatile("s_waitcnt vmcnt(8)\n\ts_barrier" ::: "memory");  // tile 0 landed

  // Main loop over tiles 0..14 (tile 15 peeled).
  #pragma unroll 2
  for (int t = 0; t < D_ / BK - 1; ++t) {
    const int curb = t & 1, nxtb = curb ^ 1;
    const uint16_t* sAc = sA[curb];
    const uint16_t* sBc = sB[curb];
    const bool doStage = (t >= 1);
    const int kn = t + 1;

    // B fragments for the whole tile (kk-outer read order).
    bf16x8 bv[4][2];
    #pragma unroll
    for (int kk = 0; kk < 2; kk++)
      #pragma unroll
      for (int tn = 0; tn < 4; tn++)
        bv[tn][kk] = *(const bf16x8*)&sBc[bBase + tn * 1024 + koff[kk]];

    // ---- half 1: clusters 0,1 (rows 0..63 of the wave half) ----
    if (doStage) { STAGE_A(nxtb, kn, 0); STAGE_A(nxtb, kn, 2); }
    CLUSTER(0);
    if (doStage) { STAGE_B(nxtb, kn, 0); STAGE_B(nxtb, kn, 1); }
    CLUSTER(1);
    asm volatile("s_waitcnt vmcnt(4)\n\ts_barrier" ::: "memory");  // A1/A3(t)

    // ---- half 2: clusters 2,3 (rows 64..127 — the A1/A3 units) ----
    if (doStage) { STAGE_B(nxtb, kn, 2); STAGE_B(nxtb, kn, 3); }
    CLUSTER(2);
    if (doStage) { STAGE_A(nxtb, kn, 1); STAGE_A(nxtb, kn, 3); }
    CLUSTER(3);
    asm volatile("s_waitcnt vmcnt(2)\n\ts_barrier" ::: "memory");  // t+1 6 units
  }
#undef STAGE_A
#undef STAGE_B

  // ---- Peeled tail: tile 15 (buffer 1). Drain the last 2 in-flight loads,
  // barrier so ALL waves' contributions have landed, then plain reads + MFMA.
  asm volatile("s_waitcnt vmcnt(0)\n\ts_barrier" ::: "memory");
  {
    const uint16_t* sAc = sA[1];
    const uint16_t* sBc = sB[1];
    bf16x8 bv[4][2];
    #pragma unroll
    for (int kk = 0; kk < 2; kk++)
      #pragma unroll
      for (int tn = 0; tn < 4; tn++)
        bv[tn][kk] = *(const bf16x8*)&sBc[bBase + tn * 1024 + koff[kk]];
    CLUSTER(0); CLUSTER(1); CLUSTER(2); CLUSTER(3);
  }
#undef CLUSTER

  // Epilogue. D layout: col=lane&15, row=q*4+i. h(tp) = hB + tp*16; the two
  // tp stores per row are 64B apart -> fill one 128B line adjacently.
  // Scan fusion: compose in-lane over i, across q via 2 ordered shfl_xor
  // steps, across m&3 in-lane; q==0 lanes write S[b][nc][h] (fp16-rounded
  // values -> bit-identical to the old scan_chunk kernel).
  const int bIdx = mTile >> 12;                 // batch index
  const int nc0  = (mTile & (S_ - 1)) >> 6;     // first 64-chunk of this tile
  const int hB   = (nTile >> 1) + wn * 32 + mn; // tp0 column; tp1 = hB+16
  const float bz0 = bz[hB],      bh0 = bh[hB];
  const float bz1 = bz[hB + 16], bh1 = bh[hB + 16];
  float Cr0 = 1.f, Vr0 = 0.f, Cr1 = 1.f, Vr1 = 0.f;
  #pragma unroll
  for (int m = 0; m < 8; ++m) {
    const int row0 = mTile + wm * 128 + m * 16 + q * 4;
    float Ct0 = 1.f, Vt0 = 0.f, Ct1 = 1.f, Vt1 = 0.f;
    #pragma unroll
    for (int i = 0; i < 4; ++i) {
      const size_t rb = (size_t)(row0 + i) * H_;
      float kv0 = acc[m][0][i] + bz0, pv0 = acc[m][1][i] + bh0;
      float kv1 = acc[m][2][i] + bz1, pv1 = acc[m][3][i] + bh1;
      float c0 = __builtin_amdgcn_rcpf(1.0f + __expf(kv0));
      float v0 = (1.0f - c0) * gfun(pv0);
      float c1 = __builtin_amdgcn_rcpf(1.0f + __expf(kv1));
      float v1 = (1.0f - c1) * gfun(pv1);
      union { _Float16 h2[2]; uint32_t u; } pk0, pk1;
      pk0.h2[0] = (_Float16)c0; pk0.h2[1] = (_Float16)v0;
      pk1.h2[0] = (_Float16)c1; pk1.h2[1] = (_Float16)v1;
      cv[rb + hB]      = pk0.u;
      cv[rb + hB + 16] = pk1.u;
      float cr0 = (float)pk0.h2[0], vr0 = (float)pk0.h2[1];
      float cr1 = (float)pk1.h2[0], vr1 = (float)pk1.h2[1];
      Vt0 = cr0 * Vt0 + vr0; Ct0 *= cr0;
      Vt1 = cr1 * Vt1 + vr1; Ct1 *= cr1;
    }
    // q-compose, ordered (a-before-b: C=Ca*Cb, V=Cb*Va+Vb), both tp.
    {
      float Cp, Vp;
      Cp = __shfl_xor(Ct0, 16); Vp = __shfl_xor(Vt0, 16);
      Vt0 = (q & 1) ? (Ct0 * Vp + Vt0) : (Cp * Vt0 + Vp); Ct0 *= Cp;
      Cp = __shfl_xor(Ct0, 32); Vp = __shfl_xor(Vt0, 32);
      Vt0 = (q & 2) ? (Ct0 * Vp + Vt0) : (Cp * Vt0 + Vp); Ct0 *= Cp;
      Cp = __shfl_xor(Ct1, 16); Vp = __shfl_xor(Vt1, 16);
      Vt1 = (q & 1) ? (Ct1 * Vp + Vt1) : (Cp * Vt1 + Vp); Ct1 *= Cp;
      Cp = __shfl_xor(Ct1, 32); Vp = __shfl_xor(Vt1, 32);
      Vt1 = (q & 2) ? (Ct1 * Vp + Vt1) : (Cp * Vt1 + Vp); Ct1 *= Cp;
    }
    if ((m & 3) == 0) { Cr0 = Ct0; Vr0 = Vt0; Cr1 = Ct1; Vr1 = Vt1; }
    else {
      Vr0 = Ct0 * Vr0 + Vt0; Cr0 *= Ct0;
      Vr1 = Ct1 * Vr1 + Vt1; Cr1 *= Ct1;
    }
    if ((m & 3) == 3 && q == 0) {
      const int nc = nc0 + wm * 2 + (m >> 2);
      const size_t sidx = ((size_t)(bIdx * NC_ + nc) << 10);
      Sc[sidx + hB] = Cr0; Sc[sidx + hB + 16] = Cr1;
      Sv[sidx + hB] = Vr0; Sv[sidx + hB + 16] = Vr1;
    }
  }
}

// ---------------- prefix pass: raw chunk states -> exclusive prefix states ----
// Thread per (b,h): P_excl[b][nc] = S[b][0] ∘ ... ∘ S[b][nc-1] (identity at 0).
__global__ __launch_bounds__(256) void prefix_kernel(
    const float* __restrict__ Sc, const float* __restrict__ Sv,
    float* __restrict__ Pc, float* __restrict__ Pv) {
  const int u = blockIdx.x * 256 + threadIdx.x;  // 8192 threads
  const int b = u >> 10, h = u & 1023;
  float C = 1.0f, V = 0.0f;
  #pragma unroll 4
  for (int nc = 0; nc < NC_; nc++) {
    const size_t idx = ((size_t)(b * NC_ + nc) << 10) + h;
    Pc[idx] = C; Pv[idx] = V;
    const float sc = Sc[idx], sv = Sv[idx];
    V = sc * V + sv;     // existing ∘ S
    C = C * sc;
  }
}

// ---------------- scan apply: single-compose carry-in + 64-step chunk ----------
__global__ __launch_bounds__(256) void scan_apply_kernel(
    const uint32_t* __restrict__ cv, const float4* __restrict__ Pc,
    const float4* __restrict__ Pv, const float* __restrict__ h0,
    float4* __restrict__ out) {
  const int tid = threadIdx.x;
  const int nc = blockIdx.x, b = blockIdx.y;
  const uint4* cv4 = (const uint4*)cv;

  // Carry-in: H = g(h0) then ONE affine compose with the exclusive prefix.
  float Hr[4];
  #pragma unroll
  for (int j = 0; j < 4; j++) Hr[j] = gfun(h0[(size_t)b * H_ + tid * 4 + j]);
  {
    const size_t pidx = (size_t)(b * NC_ + nc) * (H_ / 4) + tid;
    const float4 Cq = Pc[pidx], Vq = Pv[pidx];
    Hr[0] = Cq.x * Hr[0] + Vq.x;
    Hr[1] = Cq.y * Hr[1] + Vq.y;
    Hr[2] = Cq.z * Hr[2] + Vq.z;
    Hr[3] = Cq.w * Hr[3] + Vq.w;
  }

  size_t base = (size_t)(b * S_ + nc * L_) * (H_ / 4) + tid;
  #pragma unroll 4
  for (int t = 0; t < L_; t++) {
    size_t idx = base + (size_t)t * (H_ / 4);
    uint4 w = cv4[idx];
    float c, v;
    unpack_cv(w.x, c, v); Hr[0] = c * Hr[0] + v;
    unpack_cv(w.y, c, v); Hr[1] = c * Hr[1] + v;
    unpack_cv(w.z, c, v); Hr[2] = c * Hr[2] + v;
    unpack_cv(w.w, c, v); Hr[3] = c * Hr[3] + v;
    out[idx] = (float4){Hr[0], Hr[1], Hr[2], Hr[3]};
  }
}

extern "C" void kernel_launch(void* const* d_in, const int* in_sizes, int n_in,
                              void* d_out, int out_size, void* d_ws, size_t ws_size,
                              hipStream_t stream) {
  const float* x  = (const float*)d_in[0];
  const float* h0 = (const float*)d_in[1];
  const float* Wz = (const float*)d_in[2];
  const float* bz = (const float*)d_in[3];
  const float* Wh = (const float*)d_in[4];
  const float* bh = (const float*)d_in[5];
  float* out = (float*)d_out;

  // Workspace layout (~202 MB): xb is dead after the GEMM; prefix-state
  // buffers alias its region. Raw chunk states Sc/Sv live in the first 4 MB
  // of d_out (scratch until scan_apply overwrites).
  char* ws = (char*)d_ws;
  uint16_t* xb  = (uint16_t*)ws; ws += (size_t)M_ * D_ * 2;      // 64 MB
  uint16_t* Wcb = (uint16_t*)ws; ws += (size_t)NT_ * D_ * 2;     // 4 MB
  uint32_t* cvb = (uint32_t*)ws; ws += (size_t)M_ * H_ * 4;      // 134 MB
  char* alias = (char*)xb;
  float* Pc = (float*)alias; alias += (size_t)B_ * NC_ * H_ * 4;   // 2 MB
  float* Pv = (float*)alias; alias += (size_t)B_ * NC_ * H_ * 4;   // 2 MB
  float* Sc = out;                                                 // 2 MB scratch
  float* Sv = out + (size_t)B_ * NC_ * H_;                         // 2 MB scratch

  // 1) convert x -> bf16; interleave Wz/Wh -> Wc (2048x1024 bf16)
  cvt_all_kernel<<<dim3(2048), 256, 0, stream>>>(x, Wz, Wh, xb, Wcb);

  // 2) GEMM + activation -> packed (c,v); also emits 64-step chunk states
  fused_gemm_kernel<<<dim3((NT_ / 256) * (M_ / 256)), 512, 0, stream>>>(
      xb, Wcb, bz, bh, cvb, Sc, Sv);

  // 3) tiny prefix pass over chunk states (8 MB traffic)
  prefix_kernel<<<dim3(B_ * H_ / 256), 256, 0, stream>>>(Sc, Sv, Pc, Pv);

  // 4) apply with single-compose carry-in
  scan_apply_kernel<<<dim3(NC_, B_), 256, 0, stream>>>(
      cvb, (const float4*)Pc, (const float4*)Pv, h0, (float4*)out);
}